// Round 2
// baseline (576.664 us; speedup 1.0000x reference)
//
#include <hip/hip_runtime.h>
#include <cstdint>

typedef unsigned short u16;
typedef __bf16 bf16x8 __attribute__((ext_vector_type(8)));
typedef float f32x4 __attribute__((ext_vector_type(4)));

constexpr int Bc = 2, Sc = 2048, Dc = 1024, Hc = 16, DHc = 64;

__device__ __forceinline__ u16 f2bf(float f) {
  uint32_t u = __builtin_bit_cast(uint32_t, f);
  u += 0x7fffu + ((u >> 16) & 1u);
  return (u16)(u >> 16);
}
__device__ __forceinline__ float bf2f(u16 h) {
  uint32_t u = ((uint32_t)h) << 16;
  return __builtin_bit_cast(float, u);
}
__device__ __forceinline__ f32x4 mfma16(bf16x8 a, bf16x8 b, f32x4 c) {
  return __builtin_amdgcn_mfma_f32_16x16x32_bf16(a, b, c, 0, 0, 0);
}

// ---------------- f32 -> bf16 conversion, 4 elems/thread ----------------
__global__ __launch_bounds__(256) void cvt_kernel(const float* __restrict__ in,
                                                  u16* __restrict__ out, int n4) {
  int i = blockIdx.x * 256 + threadIdx.x;
  if (i >= n4) return;
  float4 v = reinterpret_cast<const float4*>(in)[i];
  ushort4 o;
  o.x = f2bf(v.x); o.y = f2bf(v.y); o.z = f2bf(v.z); o.w = f2bf(v.w);
  reinterpret_cast<ushort4*>(out)[i] = o;
}

// ---------------- generic bf16 GEMM: C[m][n] = (sum_k A[m][k]*B[n][k] + bias[n]) * scale
__global__ __launch_bounds__(256) void gemm_bt(
    const u16* __restrict__ A, const u16* __restrict__ Bw,
    const float* __restrict__ bias, int M, int N, int K, float scale,
    u16* __restrict__ outb, float* __restrict__ outf,
    int DHn, long strideB, long strideS, long strideH, long strideE) {
  constexpr int LDK = 40;  // 32 + 8 pad -> conflict-free ds_read_b128
  __shared__ u16 As[128 * LDK];
  __shared__ u16 Bs[128 * LDK];
  const int tid = threadIdx.x;
  const int lane = tid & 63;
  const int w = tid >> 6, wm = w >> 1, wn = w & 1;
  const int lo = lane & 15, hi = lane >> 4;
  const int m0 = blockIdx.y * 128, n0 = blockIdx.x * 128;
  const f32x4 vzero = {0.f, 0.f, 0.f, 0.f};

  f32x4 acc[4][4];
  #pragma unroll
  for (int i = 0; i < 4; ++i)
    #pragma unroll
    for (int j = 0; j < 4; ++j) acc[i][j] = vzero;

  for (int k0 = 0; k0 < K; k0 += 32) {
    #pragma unroll
    for (int it = 0; it < 2; ++it) {
      const int e = (tid + it * 256) * 8;
      const int r = e >> 5, c = e & 31;
      *reinterpret_cast<uint4*>(&As[r * LDK + c]) =
          *reinterpret_cast<const uint4*>(&A[(long)(m0 + r) * K + k0 + c]);
      int nr = n0 + r; nr = nr < N ? nr : N - 1;  // clamp (vproj N=64)
      *reinterpret_cast<uint4*>(&Bs[r * LDK + c]) =
          *reinterpret_cast<const uint4*>(&Bw[(long)nr * K + k0 + c]);
    }
    __syncthreads();
    bf16x8 af[4], bfr[4];
    #pragma unroll
    for (int mi = 0; mi < 4; ++mi)
      af[mi] = *reinterpret_cast<const bf16x8*>(&As[(wm * 64 + mi * 16 + lo) * LDK + hi * 8]);
    #pragma unroll
    for (int nj = 0; nj < 4; ++nj)
      bfr[nj] = *reinterpret_cast<const bf16x8*>(&Bs[(wn * 64 + nj * 16 + lo) * LDK + hi * 8]);
    #pragma unroll
    for (int mi = 0; mi < 4; ++mi)
      #pragma unroll
      for (int nj = 0; nj < 4; ++nj)
        acc[mi][nj] = mfma16(af[mi], bfr[nj], acc[mi][nj]);
    __syncthreads();
  }

  #pragma unroll
  for (int nj = 0; nj < 4; ++nj) {
    const int n = n0 + wn * 64 + nj * 16 + lo;
    if (n >= N) continue;
    const float bb = bias ? bias[n] : 0.f;
    const int hh = n / DHn, ee = n % DHn;
    #pragma unroll
    for (int mi = 0; mi < 4; ++mi) {
      #pragma unroll
      for (int r = 0; r < 4; ++r) {
        const int mm = m0 + wm * 64 + mi * 16 + hi * 4 + r;
        const int bidx = mm >> 11, ss = mm & 2047;  // S = 2048
        const long idx = bidx * strideB + ss * strideS + hh * strideH + ee * strideE;
        const float val = (acc[mi][nj][r] + bb) * scale;
        if (outf) outf[idx] = val;
        else outb[idx] = f2bf(val);
      }
    }
  }
}

// ---------------- flash pass: per-row m & 1/l + PV accumulation (no attn store)
// qh,kh: [B,H,S,DH] bf16 (qh pre-scaled). vT: [B,DH,S] bf16. outh: [B,H,S,DH] bf16.
// mrow,lrow: [B*H*S] f32 (lrow holds INVERSE denom).
__global__ __launch_bounds__(256) void flash_kernel(
    const u16* __restrict__ qh, const u16* __restrict__ kh,
    const u16* __restrict__ vT, u16* __restrict__ outh,
    float* __restrict__ mrow, float* __restrict__ lrow) {
  __shared__ u16 plds[4 * 16 * 40];  // per-wave P-transpose buffer, padded
  const int tid = threadIdx.x;
  const int lane = tid & 63, w = tid >> 6;
  const int lo = lane & 15, hi = lane >> 4;
  const int blk = blockIdx.x;
  const int sb = blk & 31, h = (blk >> 5) & 15, b = blk >> 9;
  const int s0 = sb * 64 + w * 16;
  const int smax = s0 + 15;
  const long bh = (long)(b * Hc + h) * Sc;
  const f32x4 vzero = {0.f, 0.f, 0.f, 0.f};

  bf16x8 qa0, qa1;
  {
    const u16* qp = &qh[(bh + s0 + lo) * DHc];
    qa0 = *reinterpret_cast<const bf16x8*>(&qp[hi * 8]);
    qa1 = *reinterpret_cast<const bf16x8*>(&qp[32 + hi * 8]);
  }

  // ---- pass 1: online max/sum over causal range ----
  float mr[4], lr[4];
  #pragma unroll
  for (int r = 0; r < 4; ++r) { mr[r] = -1e30f; lr[r] = 0.f; }

  for (int t0 = 0; t0 <= smax; t0 += 16) {
    const u16* kp = &kh[(bh + t0 + lo) * DHc];
    bf16x8 kb0 = *reinterpret_cast<const bf16x8*>(&kp[hi * 8]);
    bf16x8 kb1 = *reinterpret_cast<const bf16x8*>(&kp[32 + hi * 8]);
    f32x4 z = vzero;
    z = mfma16(qa0, kb0, z);
    z = mfma16(qa1, kb1, z);
    const int t = t0 + lo;
    #pragma unroll
    for (int r = 0; r < 4; ++r) {
      const int s = s0 + hi * 4 + r;
      const bool ok = (t <= s);
      const float zv = ok ? z[r] : -1e30f;
      const float mn = fmaxf(mr[r], zv);
      const float p = ok ? __expf(z[r] - mn) : 0.f;
      lr[r] = lr[r] * __expf(mr[r] - mn) + p;
      mr[r] = mn;
    }
  }
  // butterfly reduce across the 16 column-lanes
  #pragma unroll
  for (int r = 0; r < 4; ++r) {
    #pragma unroll
    for (int dd = 1; dd < 16; dd <<= 1) {
      const float mo = __shfl_xor(mr[r], dd);
      const float lx = __shfl_xor(lr[r], dd);
      const float mn = fmaxf(mr[r], mo);
      lr[r] = lr[r] * __expf(mr[r] - mn) + lx * __expf(mo - mn);
      mr[r] = mn;
    }
    lr[r] = 1.f / lr[r];  // inverse denom
  }
  if (lo == 0) {
    #pragma unroll
    for (int r = 0; r < 4; ++r) {
      mrow[bh + s0 + hi * 4 + r] = mr[r];
      lrow[bh + s0 + hi * 4 + r] = lr[r];
    }
  }

  // ---- pass 2: recompute live region, accumulate PV (normalized) ----
  f32x4 acco[4];
  #pragma unroll
  for (int eb = 0; eb < 4; ++eb) acco[eb] = vzero;
  u16* pbuf = &plds[w * 16 * 40];

  for (int tc = 0; tc <= smax; tc += 32) {
    float pv[2][4];
    #pragma unroll
    for (int ti = 0; ti < 2; ++ti) {
      const int t0 = tc + ti * 16;
      const u16* kp = &kh[(bh + t0 + lo) * DHc];
      bf16x8 kb0 = *reinterpret_cast<const bf16x8*>(&kp[hi * 8]);
      bf16x8 kb1 = *reinterpret_cast<const bf16x8*>(&kp[32 + hi * 8]);
      f32x4 z = vzero;
      z = mfma16(qa0, kb0, z);
      z = mfma16(qa1, kb1, z);
      const int t = t0 + lo;
      #pragma unroll
      for (int r = 0; r < 4; ++r) {
        const int s = s0 + hi * 4 + r;
        pv[ti][r] = (t <= s) ? __expf(z[r] - mr[r]) * lr[r] : 0.f;
      }
    }
    // transpose P tile via per-wave LDS into A-fragment layout
    #pragma unroll
    for (int ti = 0; ti < 2; ++ti)
      #pragma unroll
      for (int r = 0; r < 4; ++r)
        pbuf[(hi * 4 + r) * 40 + ti * 16 + lo] = f2bf(pv[ti][r]);
    asm volatile("s_waitcnt lgkmcnt(0)" ::: "memory");
    __builtin_amdgcn_sched_barrier(0);
    bf16x8 pa = *reinterpret_cast<const bf16x8*>(&pbuf[lo * 40 + hi * 8]);
    #pragma unroll
    for (int eb = 0; eb < 4; ++eb) {
      bf16x8 vb = *reinterpret_cast<const bf16x8*>(
          &vT[((long)b * DHc + eb * 16 + lo) * Sc + tc + hi * 8]);
      acco[eb] = mfma16(pa, vb, acco[eb]);
    }
  }
  #pragma unroll
  for (int eb = 0; eb < 4; ++eb)
    #pragma unroll
    for (int r = 0; r < 4; ++r) {
      const int s = s0 + hi * 4 + r;
      outh[(bh + s) * DHc + eb * 16 + lo] = f2bf(acco[eb][r]);
    }
}

// ---------------- attn matrix writer: one 128x128 tile per block
// attn_out[b,s,h,t] = (t<=s) ? exp(qh[s]·kh[t] - m[s]) * linv[s] : 0
__global__ __launch_bounds__(256) void attn_write_kernel(
    const u16* __restrict__ qh, const u16* __restrict__ kh,
    const float* __restrict__ mrow, const float* __restrict__ lrow,
    float* __restrict__ attn_out) {
  const int tt = blockIdx.x, st = blockIdx.y, bhz = blockIdx.z;
  const int b = bhz >> 4, h = bhz & 15;
  const int s0 = st * 128, t0 = tt * 128;
  const int tid = threadIdx.x;
  const long rowstride = (long)Hc * Sc;
  float* aout = attn_out + (long)b * Sc * rowstride + (long)h * Sc;

  if (tt > st) {  // fully masked tile: coalesced zero fill
    const int r0 = tid >> 5, c0 = (tid & 31) * 4;
    const float4 z4 = {0.f, 0.f, 0.f, 0.f};
    #pragma unroll
    for (int pp = 0; pp < 16; ++pp) {
      const int s = s0 + pp * 8 + r0;
      *reinterpret_cast<float4*>(&aout[(long)s * rowstride + t0 + c0]) = z4;
    }
    return;
  }

  constexpr int LDK = 72;  // 64 + 8 pad
  __shared__ u16 As[128 * LDK];
  __shared__ u16 Bs[128 * LDK];
  const long bhS = (long)bhz * Sc;
  {
    const u16* qp = qh + (bhS + s0) * DHc;
    const u16* kp = kh + (bhS + t0) * DHc;
    #pragma unroll
    for (int it = 0; it < 4; ++it) {
      const int e = (tid + it * 256) * 8;  // 0..8191
      const int r = e >> 6, c = e & 63;
      *reinterpret_cast<uint4*>(&As[r * LDK + c]) =
          *reinterpret_cast<const uint4*>(&qp[r * 64 + c]);
      *reinterpret_cast<uint4*>(&Bs[r * LDK + c]) =
          *reinterpret_cast<const uint4*>(&kp[r * 64 + c]);
    }
  }
  __syncthreads();

  const int lane = tid & 63, w = tid >> 6, wm = w >> 1, wn = w & 1;
  const int lo = lane & 15, hi = lane >> 4;
  const f32x4 vzero = {0.f, 0.f, 0.f, 0.f};
  f32x4 acc[4][4];
  #pragma unroll
  for (int i = 0; i < 4; ++i)
    #pragma unroll
    for (int j = 0; j < 4; ++j) acc[i][j] = vzero;

  #pragma unroll
  for (int k0 = 0; k0 < 64; k0 += 32) {
    bf16x8 af[4], bfr[4];
    #pragma unroll
    for (int mi = 0; mi < 4; ++mi)
      af[mi] = *reinterpret_cast<const bf16x8*>(&As[(wm * 64 + mi * 16 + lo) * LDK + k0 + hi * 8]);
    #pragma unroll
    for (int nj = 0; nj < 4; ++nj)
      bfr[nj] = *reinterpret_cast<const bf16x8*>(&Bs[(wn * 64 + nj * 16 + lo) * LDK + k0 + hi * 8]);
    #pragma unroll
    for (int mi = 0; mi < 4; ++mi)
      #pragma unroll
      for (int nj = 0; nj < 4; ++nj)
        acc[mi][nj] = mfma16(af[mi], bfr[nj], acc[mi][nj]);
  }

  #pragma unroll
  for (int mi = 0; mi < 4; ++mi) {
    #pragma unroll
    for (int r = 0; r < 4; ++r) {
      const int s = s0 + wm * 64 + mi * 16 + hi * 4 + r;
      const float mv = mrow[bhS + s];
      const float lv = lrow[bhS + s];
      float* rowp = &aout[(long)s * rowstride];
      #pragma unroll
      for (int nj = 0; nj < 4; ++nj) {
        const int t = t0 + wn * 64 + nj * 16 + lo;
        rowp[t] = (t <= s) ? __expf(acc[mi][nj][r] - mv) * lv : 0.f;
      }
    }
  }
}

// ---------------- mean over heads
__global__ __launch_bounds__(256) void mean_kernel(const u16* __restrict__ outh,
                                                   u16* __restrict__ meanb) {
  const int idx = blockIdx.x * 256 + threadIdx.x;  // 32768 threads
  const int bs = idx >> 3;
  const int e0 = (idx & 7) * 8;
  const int b = bs >> 11, s = bs & 2047;
  float acc[8];
  #pragma unroll
  for (int j = 0; j < 8; ++j) acc[j] = 0.f;
  for (int h = 0; h < Hc; ++h) {
    alignas(16) u16 tmp[8];
    *reinterpret_cast<uint4*>(tmp) =
        *reinterpret_cast<const uint4*>(&outh[((long)(b * Hc + h) * Sc + s) * DHc + e0]);
    #pragma unroll
    for (int j = 0; j < 8; ++j) acc[j] += bf2f(tmp[j]);
  }
  alignas(16) u16 o[8];
  #pragma unroll
  for (int j = 0; j < 8; ++j) o[j] = f2bf(acc[j] * 0.0625f);
  *reinterpret_cast<uint4*>(&meanb[(long)bs * DHc + e0]) = *reinterpret_cast<const uint4*>(o);
}

extern "C" void kernel_launch(void* const* d_in, const int* in_sizes, int n_in,
                              void* d_out, int out_size, void* d_ws, size_t ws_size,
                              hipStream_t stream) {
  (void)in_sizes; (void)n_in; (void)out_size; (void)ws_size;
  const float* q  = (const float*)d_in[0];
  const float* k  = (const float*)d_in[1];
  const float* v  = (const float*)d_in[2];
  const float* Wv = (const float*)d_in[4];
  const float* bv = (const float*)d_in[5];
  const float* Wq = (const float*)d_in[6];
  const float* bq = (const float*)d_in[7];
  const float* Wk = (const float*)d_in[8];
  const float* bk = (const float*)d_in[9];
  const float* Wo = (const float*)d_in[10];

  char* ws = (char*)d_ws;
  u16* qbf   = (u16*)(ws + 0);          // 8.0 MB (dead after qh gemm; reused for m/linv)
  u16* kbf   = (u16*)(ws + 8388608);
  u16* vbf   = (u16*)(ws + 16777216);
  u16* Wqbf  = (u16*)(ws + 25165824);   // 2 MB
  u16* Wkbf  = (u16*)(ws + 27262976);
  u16* Wvbf  = (u16*)(ws + 29360128);   // 128 KB
  u16* Wobf  = (u16*)(ws + 29491200);
  u16* qhb   = (u16*)(ws + 29622272);   // 8 MB  [B,H,S,DH]
  u16* khb   = (u16*)(ws + 38010880);
  u16* vTb   = (u16*)(ws + 46399488);   // 512 KB [B,DH,S]
  u16* outh  = (u16*)(ws + 46923776);   // 8 MB  [B,H,S,DH]
  u16* meanb = (u16*)(ws + 55312384);   // 512 KB
  // m/linv live in qbf's region (qbf dead once the qh GEMM has run)
  float* mrow = (float*)(ws + 0);        // 256 KB [B*H*S]
  float* lrow = (float*)(ws + 262144);   // 256 KB

  float* outp  = (float*)d_out;
  float* attnp = (float*)d_out + (long)Bc * Sc * Dc;

  auto cvt = [&](const float* in, u16* out, int n) {
    cvt_kernel<<<(n / 4 + 255) / 256, 256, 0, stream>>>(in, out, n / 4);
  };
  cvt(q,  qbf,  Bc * Sc * Dc);
  cvt(k,  kbf,  Bc * Sc * Dc);
  cvt(v,  vbf,  Bc * Sc * Dc);
  cvt(Wq, Wqbf, Hc * DHc * Dc);
  cvt(Wk, Wkbf, Hc * DHc * Dc);
  cvt(Wv, Wvbf, DHc * Dc);
  cvt(Wo, Wobf, Dc * DHc);

  const int M = Bc * Sc;  // 4096
  gemm_bt<<<dim3(8, 32), 256, 0, stream>>>(qbf, Wqbf, bq, M, 1024, 1024, 0.125f,
      qhb, nullptr, 64, 2097152L, 64L, 131072L, 1L);
  gemm_bt<<<dim3(8, 32), 256, 0, stream>>>(kbf, Wkbf, bk, M, 1024, 1024, 1.0f,
      khb, nullptr, 64, 2097152L, 64L, 131072L, 1L);
  gemm_bt<<<dim3(1, 32), 256, 0, stream>>>(vbf, Wvbf, bv, M, 64, 1024, 1.0f,
      vTb, nullptr, 64, 131072L, 1L, 0L, 2048L);

  flash_kernel<<<Bc * Hc * (Sc / 64), 256, 0, stream>>>(qhb, khb, vTb, outh, mrow, lrow);

  attn_write_kernel<<<dim3(16, 16, Bc * Hc), 256, 0, stream>>>(qhb, khb, mrow, lrow, attnp);

  mean_kernel<<<128, 256, 0, stream>>>(outh, meanb);

  gemm_bt<<<dim3(8, 32), 256, 0, stream>>>(meanb, Wobf, nullptr, M, 1024, 64, 1.0f,
      nullptr, outp, 1024, 2097152L, 1024L, 0L, 1L);
}

// Round 3
// 364.417 us; speedup vs baseline: 1.5824x; 1.5824x over previous
//
#include <hip/hip_runtime.h>
#include <cstdint>

typedef unsigned short u16;
typedef __bf16 bf16x8 __attribute__((ext_vector_type(8)));
typedef float f32x4 __attribute__((ext_vector_type(4)));

constexpr int Bc = 2, Sc = 2048, Dc = 1024, Hc = 16, DHc = 64;

__device__ __forceinline__ u16 f2bf(float f) {
  uint32_t u = __builtin_bit_cast(uint32_t, f);
  u += 0x7fffu + ((u >> 16) & 1u);
  return (u16)(u >> 16);
}
__device__ __forceinline__ float bf2f(u16 h) {
  uint32_t u = ((uint32_t)h) << 16;
  return __builtin_bit_cast(float, u);
}
__device__ __forceinline__ f32x4 mfma16(bf16x8 a, bf16x8 b, f32x4 c) {
  return __builtin_amdgcn_mfma_f32_16x16x32_bf16(a, b, c, 0, 0, 0);
}

// ---------------- f32 -> bf16 conversion, 4 elems/thread ----------------
__global__ __launch_bounds__(256) void cvt_kernel(const float* __restrict__ in,
                                                  u16* __restrict__ out, int n4) {
  int i = blockIdx.x * 256 + threadIdx.x;
  if (i >= n4) return;
  float4 v = reinterpret_cast<const float4*>(in)[i];
  ushort4 o;
  o.x = f2bf(v.x); o.y = f2bf(v.y); o.z = f2bf(v.z); o.w = f2bf(v.w);
  reinterpret_cast<ushort4*>(out)[i] = o;
}

// ---------------- generic bf16 GEMM: C[m][n] = (sum_k A[m][k]*B[n][k] + bias[n]) * scale
__global__ __launch_bounds__(256) void gemm_bt(
    const u16* __restrict__ A, const u16* __restrict__ Bw,
    const float* __restrict__ bias, int M, int N, int K, float scale,
    u16* __restrict__ outb, float* __restrict__ outf,
    int DHn, long strideB, long strideS, long strideH, long strideE) {
  constexpr int LDK = 40;  // 32 + 8 pad -> conflict-free ds_read_b128
  __shared__ u16 As[128 * LDK];
  __shared__ u16 Bs[128 * LDK];
  const int tid = threadIdx.x;
  const int lane = tid & 63;
  const int w = tid >> 6, wm = w >> 1, wn = w & 1;
  const int lo = lane & 15, hi = lane >> 4;
  const int m0 = blockIdx.y * 128, n0 = blockIdx.x * 128;
  const f32x4 vzero = {0.f, 0.f, 0.f, 0.f};

  f32x4 acc[4][4];
  #pragma unroll
  for (int i = 0; i < 4; ++i)
    #pragma unroll
    for (int j = 0; j < 4; ++j) acc[i][j] = vzero;

  for (int k0 = 0; k0 < K; k0 += 32) {
    #pragma unroll
    for (int it = 0; it < 2; ++it) {
      const int e = (tid + it * 256) * 8;
      const int r = e >> 5, c = e & 31;
      *reinterpret_cast<uint4*>(&As[r * LDK + c]) =
          *reinterpret_cast<const uint4*>(&A[(long)(m0 + r) * K + k0 + c]);
      int nr = n0 + r; nr = nr < N ? nr : N - 1;  // clamp (vproj N=64)
      *reinterpret_cast<uint4*>(&Bs[r * LDK + c]) =
          *reinterpret_cast<const uint4*>(&Bw[(long)nr * K + k0 + c]);
    }
    __syncthreads();
    bf16x8 af[4], bfr[4];
    #pragma unroll
    for (int mi = 0; mi < 4; ++mi)
      af[mi] = *reinterpret_cast<const bf16x8*>(&As[(wm * 64 + mi * 16 + lo) * LDK + hi * 8]);
    #pragma unroll
    for (int nj = 0; nj < 4; ++nj)
      bfr[nj] = *reinterpret_cast<const bf16x8*>(&Bs[(wn * 64 + nj * 16 + lo) * LDK + hi * 8]);
    #pragma unroll
    for (int mi = 0; mi < 4; ++mi)
      #pragma unroll
      for (int nj = 0; nj < 4; ++nj)
        acc[mi][nj] = mfma16(af[mi], bfr[nj], acc[mi][nj]);
    __syncthreads();
  }

  #pragma unroll
  for (int nj = 0; nj < 4; ++nj) {
    const int n = n0 + wn * 64 + nj * 16 + lo;
    if (n >= N) continue;
    const float bb = bias ? bias[n] : 0.f;
    const int hh = n / DHn, ee = n % DHn;
    #pragma unroll
    for (int mi = 0; mi < 4; ++mi) {
      #pragma unroll
      for (int r = 0; r < 4; ++r) {
        const int mm = m0 + wm * 64 + mi * 16 + hi * 4 + r;
        const int bidx = mm >> 11, ss = mm & 2047;  // S = 2048
        const long idx = bidx * strideB + ss * strideS + hh * strideH + ee * strideE;
        const float val = (acc[mi][nj][r] + bb) * scale;
        if (outf) outf[idx] = val;
        else outb[idx] = f2bf(val);
      }
    }
  }
}

// ---------------- fused causal attention, work-balanced strip pairs
// Each wave: strips idx and 127-idx (16 rows each) => identical work per wave.
// Per strip: pass1 online max/sum (64-col batches), pass2 recompute+store p+PV,
// then coalesced zero-fill of the fully-masked region.
// qh,kh: [B,H,S,DH] bf16 (qh pre-scaled by 1/8). vT: [B,DH,S] bf16.
// outh: [B,H,S,DH] bf16. attn_out: [B,S,H,S] f32.
__global__ __launch_bounds__(256) void attn_fused(
    const u16* __restrict__ qh, const u16* __restrict__ kh,
    const u16* __restrict__ vT, u16* __restrict__ outh,
    float* __restrict__ attn_out) {
  __shared__ u16 plds[4 * 16 * 80];  // per-wave transpose buffer, pitch 80 (conflict-free)
  const int tid = threadIdx.x;
  const int lane = tid & 63, w = tid >> 6;
  const int lo = lane & 15, hi = lane >> 4;
  const int blk = blockIdx.x;
  const int sb = blk & 15, h = (blk >> 4) & 15, b = blk >> 8;
  const long bh = (long)(b * Hc + h) * Sc;
  const long rowstride = (long)Hc * Sc;  // 32768
  float* aout = attn_out + (long)b * Sc * rowstride + (long)h * Sc;
  u16* pbuf = &plds[w * 16 * 80];
  const f32x4 vzero = {0.f, 0.f, 0.f, 0.f};
  const int idx = sb * 4 + w;  // 0..63

  #pragma unroll 1
  for (int sp = 0; sp < 2; ++sp) {
    const int strip = sp ? 127 - idx : idx;
    const int s0 = strip * 16;
    const int smax = s0 + 15;
    const int send = (smax / 64 + 1) * 64;  // end of live region, 64-aligned
    const int srow = s0 + hi * 4;

    bf16x8 qa0, qa1;
    {
      const u16* qp = &qh[(bh + s0 + lo) * DHc];
      qa0 = *reinterpret_cast<const bf16x8*>(&qp[hi * 8]);
      qa1 = *reinterpret_cast<const bf16x8*>(&qp[32 + hi * 8]);
    }

    // ---- pass 1: online max/sum, 64 cols per iteration ----
    float mr[4], lr[4];
    #pragma unroll
    for (int r = 0; r < 4; ++r) { mr[r] = -1e30f; lr[r] = 0.f; }

    for (int t0 = 0; t0 < send; t0 += 64) {
      f32x4 z[4];
      #pragma unroll
      for (int c = 0; c < 4; ++c) {
        const u16* kp = &kh[(bh + t0 + c * 16 + lo) * DHc];
        bf16x8 kb0 = *reinterpret_cast<const bf16x8*>(&kp[hi * 8]);
        bf16x8 kb1 = *reinterpret_cast<const bf16x8*>(&kp[32 + hi * 8]);
        f32x4 zz = mfma16(qa0, kb0, vzero);
        z[c] = mfma16(qa1, kb1, zz);
      }
      #pragma unroll
      for (int r = 0; r < 4; ++r) {
        const int s = srow + r;
        float mt = -1e30f;
        #pragma unroll
        for (int c = 0; c < 4; ++c) {
          const bool okc = (t0 + c * 16 + lo) <= s;
          mt = fmaxf(mt, okc ? z[c][r] : -1e30f);
        }
        const float mn = fmaxf(mr[r], mt);
        float sum = 0.f;
        #pragma unroll
        for (int c = 0; c < 4; ++c) {
          const bool okc = (t0 + c * 16 + lo) <= s;
          sum += okc ? __expf(z[c][r] - mn) : 0.f;
        }
        lr[r] = lr[r] * __expf(mr[r] - mn) + sum;
        mr[r] = mn;
      }
    }
    // butterfly reduce across the 16 column-lanes
    #pragma unroll
    for (int r = 0; r < 4; ++r) {
      #pragma unroll
      for (int dd = 1; dd < 16; dd <<= 1) {
        const float mo = __shfl_xor(mr[r], dd);
        const float lx = __shfl_xor(lr[r], dd);
        const float mn = fmaxf(mr[r], mo);
        lr[r] = lr[r] * __expf(mr[r] - mn) + lx * __expf(mo - mn);
        mr[r] = mn;
      }
      lr[r] = 1.f / lr[r];  // inverse denom
    }

    // ---- pass 2: recompute, store normalized p, accumulate PV ----
    f32x4 acco[4];
    #pragma unroll
    for (int eb = 0; eb < 4; ++eb) acco[eb] = vzero;

    for (int t0 = 0; t0 < send; t0 += 64) {
      f32x4 z[4];
      #pragma unroll
      for (int c = 0; c < 4; ++c) {
        const u16* kp = &kh[(bh + t0 + c * 16 + lo) * DHc];
        bf16x8 kb0 = *reinterpret_cast<const bf16x8*>(&kp[hi * 8]);
        bf16x8 kb1 = *reinterpret_cast<const bf16x8*>(&kp[32 + hi * 8]);
        f32x4 zz = mfma16(qa0, kb0, vzero);
        z[c] = mfma16(qa1, kb1, zz);
      }
      #pragma unroll
      for (int r = 0; r < 4; ++r) {
        const int s = srow + r;
        float* rp = aout + (long)s * rowstride + t0 + lo;
        #pragma unroll
        for (int c = 0; c < 4; ++c) {
          const bool okc = (t0 + c * 16 + lo) <= s;
          const float p = okc ? __expf(z[c][r] - mr[r]) * lr[r] : 0.f;
          rp[c * 16] = p;
          pbuf[(hi * 4 + r) * 80 + c * 16 + lo] = f2bf(p);
        }
      }
      asm volatile("s_waitcnt lgkmcnt(0)" ::: "memory");
      __builtin_amdgcn_sched_barrier(0);
      bf16x8 pa0 = *reinterpret_cast<const bf16x8*>(&pbuf[lo * 80 + hi * 8]);
      bf16x8 pa1 = *reinterpret_cast<const bf16x8*>(&pbuf[lo * 80 + 32 + hi * 8]);
      const u16* vp = &vT[((long)b * DHc + lo) * Sc + t0 + hi * 8];
      #pragma unroll
      for (int eb = 0; eb < 4; ++eb) {
        bf16x8 vb0 = *reinterpret_cast<const bf16x8*>(&vp[(long)eb * 16 * Sc]);
        bf16x8 vb1 = *reinterpret_cast<const bf16x8*>(&vp[(long)eb * 16 * Sc + 32]);
        acco[eb] = mfma16(pa0, vb0, acco[eb]);
        acco[eb] = mfma16(pa1, vb1, acco[eb]);
      }
    }

    // ---- epilogue: outh store + zero-fill masked region ----
    #pragma unroll
    for (int eb = 0; eb < 4; ++eb)
      #pragma unroll
      for (int r = 0; r < 4; ++r)
        outh[(bh + srow + r) * DHc + eb * 16 + lo] = f2bf(acco[eb][r]);

    const float4 z4 = {0.f, 0.f, 0.f, 0.f};
    for (int t0 = send; t0 < Sc; t0 += 64) {
      #pragma unroll
      for (int r = 0; r < 4; ++r)
        *reinterpret_cast<float4*>(aout + (long)(srow + r) * rowstride + t0 + lo * 4) = z4;
    }
  }
}

// ---------------- mean over heads
__global__ __launch_bounds__(256) void mean_kernel(const u16* __restrict__ outh,
                                                   u16* __restrict__ meanb) {
  const int idx = blockIdx.x * 256 + threadIdx.x;  // 32768 threads
  const int bs = idx >> 3;
  const int e0 = (idx & 7) * 8;
  const int b = bs >> 11, s = bs & 2047;
  float acc[8];
  #pragma unroll
  for (int j = 0; j < 8; ++j) acc[j] = 0.f;
  for (int h = 0; h < Hc; ++h) {
    alignas(16) u16 tmp[8];
    *reinterpret_cast<uint4*>(tmp) =
        *reinterpret_cast<const uint4*>(&outh[((long)(b * Hc + h) * Sc + s) * DHc + e0]);
    #pragma unroll
    for (int j = 0; j < 8; ++j) acc[j] += bf2f(tmp[j]);
  }
  alignas(16) u16 o[8];
  #pragma unroll
  for (int j = 0; j < 8; ++j) o[j] = f2bf(acc[j] * 0.0625f);
  *reinterpret_cast<uint4*>(&meanb[(long)bs * DHc + e0]) = *reinterpret_cast<const uint4*>(o);
}

extern "C" void kernel_launch(void* const* d_in, const int* in_sizes, int n_in,
                              void* d_out, int out_size, void* d_ws, size_t ws_size,
                              hipStream_t stream) {
  (void)in_sizes; (void)n_in; (void)out_size; (void)ws_size;
  const float* q  = (const float*)d_in[0];
  const float* k  = (const float*)d_in[1];
  const float* v  = (const float*)d_in[2];
  const float* Wv = (const float*)d_in[4];
  const float* bv = (const float*)d_in[5];
  const float* Wq = (const float*)d_in[6];
  const float* bq = (const float*)d_in[7];
  const float* Wk = (const float*)d_in[8];
  const float* bk = (const float*)d_in[9];
  const float* Wo = (const float*)d_in[10];

  char* ws = (char*)d_ws;
  u16* qbf   = (u16*)(ws + 0);          // 8.0 MB
  u16* kbf   = (u16*)(ws + 8388608);
  u16* vbf   = (u16*)(ws + 16777216);
  u16* Wqbf  = (u16*)(ws + 25165824);   // 2 MB
  u16* Wkbf  = (u16*)(ws + 27262976);
  u16* Wvbf  = (u16*)(ws + 29360128);   // 128 KB
  u16* Wobf  = (u16*)(ws + 29491200);
  u16* qhb   = (u16*)(ws + 29622272);   // 8 MB  [B,H,S,DH]
  u16* khb   = (u16*)(ws + 38010880);
  u16* vTb   = (u16*)(ws + 46399488);   // 512 KB [B,DH,S]
  u16* outh  = (u16*)(ws + 46923776);   // 8 MB  [B,H,S,DH]
  u16* meanb = (u16*)(ws + 55312384);   // 512 KB

  float* outp  = (float*)d_out;
  float* attnp = (float*)d_out + (long)Bc * Sc * Dc;

  auto cvt = [&](const float* in, u16* out, int n) {
    cvt_kernel<<<(n / 4 + 255) / 256, 256, 0, stream>>>(in, out, n / 4);
  };
  cvt(q,  qbf,  Bc * Sc * Dc);
  cvt(k,  kbf,  Bc * Sc * Dc);
  cvt(v,  vbf,  Bc * Sc * Dc);
  cvt(Wq, Wqbf, Hc * DHc * Dc);
  cvt(Wk, Wkbf, Hc * DHc * Dc);
  cvt(Wv, Wvbf, DHc * Dc);
  cvt(Wo, Wobf, Dc * DHc);

  const int M = Bc * Sc;  // 4096
  gemm_bt<<<dim3(8, 32), 256, 0, stream>>>(qbf, Wqbf, bq, M, 1024, 1024, 0.125f,
      qhb, nullptr, 64, 2097152L, 64L, 131072L, 1L);
  gemm_bt<<<dim3(8, 32), 256, 0, stream>>>(kbf, Wkbf, bk, M, 1024, 1024, 1.0f,
      khb, nullptr, 64, 2097152L, 64L, 131072L, 1L);
  gemm_bt<<<dim3(1, 32), 256, 0, stream>>>(vbf, Wvbf, bv, M, 64, 1024, 1.0f,
      vTb, nullptr, 64, 131072L, 1L, 0L, 2048L);

  attn_fused<<<512, 256, 0, stream>>>(qhb, khb, vTb, outh, attnp);

  mean_kernel<<<128, 256, 0, stream>>>(outh, meanb);

  gemm_bt<<<dim3(8, 32), 256, 0, stream>>>(meanb, Wobf, nullptr, M, 1024, 64, 1.0f,
      nullptr, outp, 1024, 2097152L, 1024L, 0L, 1L);
}